// Round 8
// baseline (259.955 us; speedup 1.0000x reference)
//
#include <hip/hip_runtime.h>
#include <hip/hip_bf16.h>

// GCN encoder: h = relu(Agg(h @ W)) x3 after input linear.
// N=20000 nodes, E=640000 edges, H=128.
// R1->R2: CSR pull-agg replaced atomics (3330->367us).
// R2->R3: bigger GEMM tiles (367->331us).
// R3->R4: parallel scan; 128-row GEMM blocks (331->274us).
// R4->R5: global-broadcast GEMM -> latency-bound regression (355us).
// R5->R6: LDS-broadcast GEMM (282us) -- LDS-pipe-bound.
// R6->R7: GEMMs on matrix pipe via 3-term bf16 split (245us).
// R7->R8: agg gathers made XCD-L2-resident: xw stored as 4 column-slices
//         [slice][N][32] (2.56MB/slice < 4MB XCD L2); block b handles slice
//         b&3 so each XCD (blockIdx%8) touches one slice only. Half-waves
//         process 2 edges per 128B-row load, 8 edges in flight,
//         cross-half shfl_xor reduce. (Old agg: random 512B rows from 10MB
//         buffer thrashed L2 -> 107MB FETCH per dispatch.)
// ws layout: [dis: N f][off: N i][csr: E i][hh: N*128 bf16][hl: N*128 bf16][xw: N*128 f]

#define HDIM 128
#define SCAN_TILE 1024

typedef __attribute__((ext_vector_type(8))) short s8v;
typedef __attribute__((ext_vector_type(4))) float f4v;

__device__ __forceinline__ ushort f2bf(float f) {
    uint u = __float_as_uint(f);
    u += 0x7FFFu + ((u >> 16) & 1u);      // round-to-nearest-even
    return (ushort)(u >> 16);
}
__device__ __forceinline__ float bf2f(ushort h) {
    return __uint_as_float(((uint)h) << 16);
}

__global__ __launch_bounds__(256) void k_zero(int* __restrict__ off, int N) {
    int i = blockIdx.x * 256 + threadIdx.x;
    if (i < N) off[i] = 0;
}

__global__ __launch_bounds__(256) void k_count(const int* __restrict__ dst,
                                               int* __restrict__ off, int E) {
    int e = blockIdx.x * 256 + threadIdx.x;
    if (e < E) atomicAdd(&off[dst[e]], 1);
}

// Block-local exclusive scan of deg (in place) + dis = rsqrt(deg+1) + block sums.
__global__ __launch_bounds__(256) void k_scan_blk(int* __restrict__ off,
                                                  float* __restrict__ dis,
                                                  int* __restrict__ bsum, int N) {
    int t = threadIdx.x;
    int base = blockIdx.x * SCAN_TILE + t * 4;
    int4 d = make_int4(0, 0, 0, 0);
    if (base + 3 < N) d = *(const int4*)(off + base);
    else {
        if (base + 0 < N) d.x = off[base + 0];
        if (base + 1 < N) d.y = off[base + 1];
        if (base + 2 < N) d.z = off[base + 2];
    }
    if (base + 0 < N) dis[base + 0] = rsqrtf((float)(d.x + 1));
    if (base + 1 < N) dis[base + 1] = rsqrtf((float)(d.y + 1));
    if (base + 2 < N) dis[base + 2] = rsqrtf((float)(d.z + 1));
    if (base + 3 < N) dis[base + 3] = rsqrtf((float)(d.w + 1));

    int tsum = d.x + d.y + d.z + d.w;
    int lane = t & 63;
    int incl = tsum;
    #pragma unroll
    for (int ofs = 1; ofs < 64; ofs <<= 1) {
        int u = __shfl_up(incl, ofs);
        if (lane >= ofs) incl += u;
    }
    __shared__ int wsum[4];
    if (lane == 63) wsum[t >> 6] = incl;
    __syncthreads();
    int w = t >> 6;
    int woff = 0;
    for (int i = 0; i < w; ++i) woff += wsum[i];

    int run = woff + incl - tsum;  // exclusive prefix (block-local)
    if (base + 0 < N) off[base + 0] = run; run += d.x;
    if (base + 1 < N) off[base + 1] = run; run += d.y;
    if (base + 2 < N) off[base + 2] = run; run += d.z;
    if (base + 3 < N) off[base + 3] = run;
    if (t == 255) bsum[blockIdx.x] = woff + incl;  // block total
}

__global__ __launch_bounds__(256) void k_scan_add(int* __restrict__ off,
                                                  const int* __restrict__ bsum, int N) {
    int bid = blockIdx.x;
    if (bid == 0) return;
    int p = 0;
    for (int i = 0; i < bid; ++i) p += bsum[i];
    int base = bid * SCAN_TILE + threadIdx.x * 4;
    if (base + 3 < N) {
        int4 v = *(const int4*)(off + base);
        v.x += p; v.y += p; v.z += p; v.w += p;
        *(int4*)(off + base) = v;
    } else {
        if (base + 0 < N) off[base + 0] += p;
        if (base + 1 < N) off[base + 1] += p;
        if (base + 2 < N) off[base + 2] += p;
    }
}

// csr fill: pos = off[dst]++ ; csr[pos] = src. After this, off[v] = excl_prefix[v+1].
__global__ __launch_bounds__(256) void k_fill(const int* __restrict__ src,
                                              const int* __restrict__ dst,
                                              int* __restrict__ off,
                                              int* __restrict__ csr, int E) {
    int e = blockIdx.x * 256 + threadIdx.x;
    if (e >= E) return;
    int pos = atomicAdd(&off[dst[e]], 1);
    csr[pos] = src[e];
}

// Convert all 4 weight matrices (fp32 128x128) into MFMA B-fragment layout,
// bf16 hi/lo planes. Per matrix: [2 planes][4 ksteps][8 ctiles][64 lanes][8] ushort.
__global__ __launch_bounds__(256) void k_wconv(const float* __restrict__ W_in,
                                               const float* __restrict__ Ws,
                                               ushort* __restrict__ Wf) {
    int idx = blockIdx.x * 256 + threadIdx.x;   // 4 * 16384
    int m = idx >> 14;
    int e = idx & 16383;
    int k = e >> 7, col = e & 127;
    const float* srcm = (m == 0) ? W_in : (Ws + (m - 1) * 16384);
    float w = srcm[k * 128 + col];
    ushort hi = f2bf(w);
    ushort lo = f2bf(w - bf2f(hi));
    int ks = k >> 5, lk = (k >> 3) & 3, j = k & 7;
    int ct = col >> 4, lane = lk * 16 + (col & 15);
    int o = m * 32768 + (ks * 8 + ct) * 512 + lane * 8 + j;
    Wf[o] = hi;
    Wf[o + 16384] = lo;
}

// x (fp32) -> hh/hl bf16 split pair.
__global__ __launch_bounds__(256) void k_xconv(const float* __restrict__ x,
                                               ushort* __restrict__ hh,
                                               ushort* __restrict__ hl, int total4) {
    int i = blockIdx.x * 256 + threadIdx.x;
    if (i >= total4) return;
    float4 v = ((const float4*)x)[i];
    ushort a0 = f2bf(v.x), a1 = f2bf(v.y), a2 = f2bf(v.z), a3 = f2bf(v.w);
    uint2 ph, pl;
    ph.x = (uint)a0 | ((uint)a1 << 16);
    ph.y = (uint)a2 | ((uint)a3 << 16);
    pl.x = (uint)f2bf(v.x - bf2f(a0)) | ((uint)f2bf(v.y - bf2f(a1)) << 16);
    pl.y = (uint)f2bf(v.z - bf2f(a2)) | ((uint)f2bf(v.w - bf2f(a3)) << 16);
    ((uint2*)hh)[i] = ph;
    ((uint2*)hl)[i] = pl;
}

// MFMA GEMM: out[M,128] = (Ahi+Alo)[M,128] @ W[128,128], 3-term bf16 split.
// Block = 4 waves, wave = one 16-row strip, full 128 cols (8 ctiles).
// BF16OUT: write hi/lo split pair row-major (plus bias);
// else fp32 (times scale) into SLICED layout [slice=col/32][row][col%32].
template<int BF16OUT>
__global__ __launch_bounds__(256) void k_mgemm(const ushort* Ahi, const ushort* Alo,
                                               const ushort* __restrict__ Wf,
                                               const float* __restrict__ bias,
                                               const float* __restrict__ scale,
                                               float* outf, ushort* outhi,
                                               ushort* outlo, int M) {
    int l = threadIdx.x & 63;
    int strip = blockIdx.x * 4 + (threadIdx.x >> 6);
    int r0 = strip * 16;
    if (r0 >= M) return;
    int lr = l & 15, lk = l >> 4;
    const ushort* pa_hi = Ahi + (r0 + lr) * HDIM + lk * 8;
    const ushort* pa_lo = Alo + (r0 + lr) * HDIM + lk * 8;

    f4v acc[8];
    #pragma unroll
    for (int c = 0; c < 8; ++c) acc[c] = (f4v){0.f, 0.f, 0.f, 0.f};

    #pragma unroll
    for (int ks = 0; ks < 4; ++ks) {
        s8v ah = *(const s8v*)(pa_hi + ks * 32);
        s8v al = *(const s8v*)(pa_lo + ks * 32);
        const ushort* wb = Wf + (ks * 8) * 512 + l * 8;
        #pragma unroll
        for (int ct = 0; ct < 8; ++ct) {
            s8v bh = *(const s8v*)(wb + ct * 512);
            s8v bl = *(const s8v*)(wb + 16384 + ct * 512);
            acc[ct] = __builtin_amdgcn_mfma_f32_16x16x32_bf16(ah, bh, acc[ct], 0, 0, 0);
            acc[ct] = __builtin_amdgcn_mfma_f32_16x16x32_bf16(ah, bl, acc[ct], 0, 0, 0);
            acc[ct] = __builtin_amdgcn_mfma_f32_16x16x32_bf16(al, bh, acc[ct], 0, 0, 0);
        }
    }

    float bb[8];
    #pragma unroll
    for (int ct = 0; ct < 8; ++ct) bb[ct] = bias ? bias[ct * 16 + lr] : 0.f;
    float sc[4];
    #pragma unroll
    for (int j = 0; j < 4; ++j) sc[j] = scale ? scale[r0 + lk * 4 + j] : 1.f;

    #pragma unroll
    for (int ct = 0; ct < 8; ++ct) {
        #pragma unroll
        for (int j = 0; j < 4; ++j) {
            int row = r0 + lk * 4 + j;
            int col = ct * 16 + lr;
            float o = (acc[ct][j] + bb[ct]) * sc[j];
            if (BF16OUT) {
                ushort h = f2bf(o);
                outhi[row * HDIM + col] = h;
                outlo[row * HDIM + col] = f2bf(o - bf2f(h));
            } else {
                int sl = ct >> 1;
                int c = ((ct & 1) << 4) | lr;
                outf[(long long)sl * M * 32 + (long long)row * 32 + c] = o;
            }
        }
    }
}

// Pull aggregation over SLICED pre-scaled xw' (xw'[sl][row][32] = dis[row]*(h@W)).
// Block b -> slice b&3; with XCD = blockIdx%8, each XCD touches one 2.56MB
// slice only -> gathers are XCD-L2-resident. Wave = one node; half-waves
// handle 2 edges per 128B-row load; 8 edges in flight; shfl_xor(32) reduce.
// LAST: write fp32 d_out; else write bf16 hi/lo split pair (row-major).
template<int LAST>
__global__ __launch_bounds__(256) void k_agg(const int* __restrict__ off,
                                             const int* __restrict__ csr,
                                             const float* __restrict__ dis,
                                             const float* __restrict__ xw,
                                             const float* __restrict__ b,
                                             float* __restrict__ outf,
                                             ushort* __restrict__ outhi,
                                             ushort* __restrict__ outlo, int N) {
    int lane = threadIdx.x & 63;
    int wv = threadIdx.x >> 6;
    int hl = lane & 31, half = lane >> 5;
    int sl = blockIdx.x & 3;
    const float* xs = xw + (long long)sl * N * 32;
    int v0 = (blockIdx.x >> 2) * 4 + wv;
    int vstride = (gridDim.x >> 2) * 4;

    float bb = b[sl * 32 + hl];

    for (int v = v0; v < N; v += vstride) {
        int start = (v > 0) ? off[v - 1] : 0;   // off is post-fill: off[v] = excl[v+1]
        int end = off[v];
        float dv = dis[v];
        float acc = (half == 0) ? xs[(long long)v * 32 + hl] : 0.f;  // self term

        int i = start;
        for (; i + 8 <= end; i += 8) {
            int ib = __builtin_amdgcn_readfirstlane(i) + half;
            int s0 = csr[ib + 0];
            int s1 = csr[ib + 2];
            int s2 = csr[ib + 4];
            int s3 = csr[ib + 6];
            float x0 = xs[(long long)s0 * 32 + hl];
            float x1 = xs[(long long)s1 * 32 + hl];
            float x2 = xs[(long long)s2 * 32 + hl];
            float x3 = xs[(long long)s3 * 32 + hl];
            acc += (x0 + x1) + (x2 + x3);
        }
        for (; i + 2 <= end; i += 2) {
            int s = csr[__builtin_amdgcn_readfirstlane(i) + half];
            acc += xs[(long long)s * 32 + hl];
        }
        if (i < end) {
            if (half == 0) {
                int s = csr[__builtin_amdgcn_readfirstlane(i)];
                acc += xs[(long long)s * 32 + hl];
            }
        }
        acc += __shfl_xor(acc, 32);

        if (half == 0) {
            float o = fmaxf(fmaf(dv, acc, bb), 0.f);
            long long oidx = (long long)v * HDIM + sl * 32 + hl;
            if (LAST) {
                outf[oidx] = o;
            } else {
                ushort h = f2bf(o);
                outhi[oidx] = h;
                outlo[oidx] = f2bf(o - bf2f(h));
            }
        }
    }
}

extern "C" void kernel_launch(void* const* d_in, const int* in_sizes, int n_in,
                              void* d_out, int out_size, void* d_ws, size_t ws_size,
                              hipStream_t stream) {
    const float* x    = (const float*)d_in[0];
    const int*   ei   = (const int*)d_in[1];   // [2, E]: first E = src, next E = dst
    const float* W_in = (const float*)d_in[2];
    const float* b_in = (const float*)d_in[3];
    const float* Ws   = (const float*)d_in[4]; // [3,128,128]
    const float* bs   = (const float*)d_in[5]; // [3,128]

    const int N = in_sizes[0] / HDIM;
    const int E = in_sizes[1] / 2;
    const int* src = ei;
    const int* dst = ei + E;

    float*  dis = (float*)d_ws;                      // N floats
    int*    off = (int*)(dis + N);                   // N ints
    int*    csr = off + N;                           // E ints (first ~32 = scan bsums, transient)
    ushort* hh  = (ushort*)(csr + E);                // N*128 bf16 (h hi)
    ushort* hl  = hh + (long long)N * HDIM;          // N*128 bf16 (h lo)
    float*  xw  = (float*)(hl + (long long)N * HDIM);// N*128 floats (sliced, dis-prescaled)
    ushort* Wf  = (ushort*)d_out;                    // 4*64KB scratch, overwritten by last agg

    int nb_N    = (N + 255) / 256;
    int nb_E    = (E + 255) / 256;
    int nb_scan = (N + SCAN_TILE - 1) / SCAN_TILE;
    int strips  = (N + 15) / 16;
    int nb_mg   = (strips + 3) / 4;
    int nb_x4   = (N * (HDIM / 4) + 255) / 256;
    int nb_agg  = 2048;

    // CSR build + dis
    k_zero    <<<nb_N,    256, 0, stream>>>(off, N);
    k_count   <<<nb_E,    256, 0, stream>>>(dst, off, E);
    k_scan_blk<<<nb_scan, 256, 0, stream>>>(off, dis, csr, N);
    k_scan_add<<<nb_scan, 256, 0, stream>>>(off, csr, N);
    k_fill    <<<nb_E,    256, 0, stream>>>(src, dst, off, csr, E);

    // weight fragments (d_out scratch) + x -> bf16 split
    k_wconv<<<256, 256, 0, stream>>>(W_in, Ws, Wf);
    k_xconv<<<nb_x4, 256, 0, stream>>>(x, hh, hl, N * (HDIM / 4));

    // h0 = x @ W_in + b_in   (bf16-split output, in place: wave reads own rows only)
    k_mgemm<1><<<nb_mg, 256, 0, stream>>>(hh, hl, Wf, b_in, nullptr,
                                          nullptr, hh, hl, N);

    for (int layer = 0; layer < 3; ++layer) {
        const ushort* Wfm = Wf + (long long)(layer + 1) * 32768;
        const float* b = bs + (long long)layer * HDIM;
        // xw' = (h @ W) * dis[row]  (fp32, sliced layout)
        k_mgemm<0><<<nb_mg, 256, 0, stream>>>(hh, hl, Wfm, nullptr, dis,
                                              xw, nullptr, nullptr, N);
        if (layer == 2)
            k_agg<1><<<nb_agg, 256, 0, stream>>>(off, csr, dis, xw, b,
                                                 (float*)d_out, nullptr, nullptr, N);
        else
            k_agg<0><<<nb_agg, 256, 0, stream>>>(off, csr, dis, xw, b,
                                                 nullptr, hh, hl, N);
    }
}